// Round 4
// baseline (267.341 us; speedup 1.0000x reference)
//
#include <hip/hip_runtime.h>

#define LN_EPS 1e-5f

// d_ws layout: int counters at byte 0..31 (8 ints, memset to 0 per launch),
// float region offsets (in floats, all 16B-aligned):
#define OFF_NP   16      // 448   node partial sums (blocks 64..511)
#define OFF_CVP  464     // 64*64 cv partials [b=h*8+c][64]
#define OFF_S    4560    // 1 (pad 16)
#define OFF_TP   4576    // 4*512 t partials [rc][n]
#define OFF_HP   6624    // 4*2048 ffn1 partials [nq][j]
#define OFF_YPP  14816   // 64*512 ffn2 partials [jc][n]
#define OFF_Y    47584   // 512 y vector (pre-LN2)
#define OFF_ST   48096   // 8: sums[4], sumsqs[4]

__device__ inline float wave_reduce(float v) {
    #pragma unroll
    for (int o = 32; o > 0; o >>= 1) v += __shfl_xor(v, o);
    return v;
}

__device__ inline float block_reduce_256(float v, float* sred, int tid) {
    v = wave_reduce(v);
    if ((tid & 63) == 0) sred[tid >> 6] = v;
    __syncthreads();
    float r = sred[0] + sred[1] + sred[2] + sred[3];
    __syncthreads();
    return r;
}

__device__ inline void arrive_c(int* c) {
    __syncthreads();
    if (threadIdx.x == 0) {
        __threadfence();  // release: flush this CU's stores device-wide
        __hip_atomic_fetch_add(c, 1, __ATOMIC_RELEASE, __HIP_MEMORY_SCOPE_AGENT);
    }
}

__device__ inline void wait_c(int* c, int target) {
    if (threadIdx.x == 0) {
        while (__hip_atomic_load(c, __ATOMIC_ACQUIRE, __HIP_MEMORY_SCOPE_AGENT) < target)
            __builtin_amdgcn_s_sleep(2);
    }
    __syncthreads();
    __threadfence();  // acquire: invalidate stale cached lines before data reads
}

__global__ __launch_bounds__(256, 2)
void fused_all(const float* __restrict__ node, const float* __restrict__ Wvs,
               const float* __restrict__ Wo, const float* __restrict__ W1,
               const float* __restrict__ b1, const float* __restrict__ W2,
               const float* __restrict__ b2, const float* __restrict__ g1,
               const float* __restrict__ be1, const float* __restrict__ g2,
               const float* __restrict__ be2, float* __restrict__ ws,
               int* __restrict__ cnt, float* __restrict__ out) {
    const int bid = blockIdx.x, tid = threadIdx.x;
    __shared__ float s_big[512];
    __shared__ float s_sm[256];
    __shared__ float4 s_sm4[256];
    __shared__ float s_sred[4];
    __shared__ float s_hl[32];

    // ---------------- P1: cv partials (blocks 0..63) / node partials (64..511)
    if (bid < 64) {
        const int h = bid >> 3, c = bid & 7;
        const int n = tid & 63, ks = tid >> 6;          // ks 0..3
        const float* w = Wvs + h * (512 * 64);
        float acc = 0.f;
        #pragma unroll
        for (int q = 0; q < 16; ++q) {
            const int k = c * 64 + ks + q * 4;
            acc += w[k * 64 + n];
        }
        s_sm[tid] = acc;
        __syncthreads();
        if (ks == 0)
            ws[OFF_CVP + bid * 64 + n] =
                s_sm[n] + s_sm[64 + n] + s_sm[128 + n] + s_sm[192 + n];
    } else {
        const float4* n4 = (const float4*)node;          // 524288 float4
        const int base = (bid - 64) * 1171;
        float acc = 0.f;
        #pragma unroll
        for (int i = 0; i < 5; ++i) {
            const int off = i * 256 + tid;
            const int idx = base + off;
            if (off < 1171 && idx < 524288) {
                const float4 v = n4[idx];
                acc += (v.x + v.y) + (v.z + v.w);
            }
        }
        const float r = block_reduce_256(acc, s_sred, tid);
        if (tid == 0) ws[OFF_NP + (bid - 64)] = r;
    }
    arrive_c(&cnt[0]);

    // ---------------- P2: t partials (blocks 0..63) + S finalize (block 64)
    if (bid < 64) {
        wait_c(&cnt[0], 512);
        // build full cv[512] in LDS (r = h*64+m)
        #pragma unroll
        for (int half = 0; half < 2; ++half) {
            const int rr = tid + half * 256;
            const int hh = rr >> 6, mm = rr & 63;
            float a = 0.f;
            #pragma unroll
            for (int c = 0; c < 8; ++c) a += ws[OFF_CVP + (hh * 8 + c) * 64 + mm];
            s_big[rr] = a;
        }
        __syncthreads();
        const int rc = bid >> 4, nch = bid & 15;         // 4 r-chunks x 16 n-chunks
        const int nl = tid & 31, rg = tid >> 5;          // 32 n, 8 r-groups
        float acc = 0.f;
        #pragma unroll
        for (int i = 0; i < 16; ++i) {
            const int r = rc * 128 + rg * 16 + i;
            acc += s_big[r] * Wo[r * 512 + nch * 32 + nl];
        }
        s_sm[rg * 32 + nl] = acc;
        __syncthreads();
        if (tid < 32) {
            float s = 0.f;
            #pragma unroll
            for (int g = 0; g < 8; ++g) s += s_sm[g * 32 + tid];
            ws[OFF_TP + rc * 512 + nch * 32 + tid] = s;
        }
        arrive_c(&cnt[1]);
    } else if (bid == 64) {
        wait_c(&cnt[0], 512);
        float v = ws[OFF_NP + tid];
        if (tid < 192) v += ws[OFF_NP + 256 + tid];
        const float s = block_reduce_256(v, s_sred, tid);
        if (tid == 0) ws[OFF_S] = s;
        arrive_c(&cnt[1]);
    }

    // ---------------- P3: LN1 (redundant) + FFN1 partial (blocks 0..255)
    if (bid < 256) {
        wait_c(&cnt[1], 65);
        const float S = ws[OFF_S];
        float x0, x1;
        {
            const int n = tid;
            x0 = S * (ws[OFF_TP + n] + ws[OFF_TP + 512 + n] +
                      ws[OFF_TP + 1024 + n] + ws[OFF_TP + 1536 + n]);
        }
        {
            const int n = tid + 256;
            x1 = S * (ws[OFF_TP + n] + ws[OFF_TP + 512 + n] +
                      ws[OFF_TP + 1024 + n] + ws[OFF_TP + 1536 + n]);
        }
        const float tot = block_reduce_256(x0 + x1, s_sred, tid);
        const float mu = tot * (1.f / 512.f);
        const float d0 = x0 - mu, d1 = x1 - mu;
        const float var = block_reduce_256(d0 * d0 + d1 * d1, s_sred, tid) * (1.f / 512.f);
        const float inv = rsqrtf(var + LN_EPS);
        s_big[tid]       = d0 * inv * g1[tid] + be1[tid];
        s_big[tid + 256] = d1 * inv * g1[tid + 256] + be1[tid + 256];
        __syncthreads();
        const int jc3 = bid >> 2, nq = bid & 3;          // 64 j-chunks x 4 n-quarters
        const int jl = tid & 31, ng = tid >> 5;          // 32 j, 8 n-groups
        float acc = 0.f;
        #pragma unroll
        for (int i = 0; i < 16; ++i) {
            const int n = nq * 128 + ng * 16 + i;
            acc += s_big[n] * W1[n * 2048 + jc3 * 32 + jl];
        }
        s_sm[ng * 32 + jl] = acc;
        __syncthreads();
        if (tid < 32) {
            float s = 0.f;
            #pragma unroll
            for (int g = 0; g < 8; ++g) s += s_sm[g * 32 + tid];
            ws[OFF_HP + nq * 2048 + jc3 * 32 + tid] = s;
        }
        arrive_c(&cnt[2]);
    }

    // ---------------- P4: h finalize + FFN2 partial (blocks 0..255)
    if (bid < 256) {
        wait_c(&cnt[2], 256);
        const int jc = bid >> 2, nc = bid & 3;           // 64 j-chunks x 4 n-chunks
        if (tid < 32) {
            const int j = jc * 32 + tid;
            const float v = ws[OFF_HP + j] + ws[OFF_HP + 2048 + j] +
                            ws[OFF_HP + 4096 + j] + ws[OFF_HP + 6144 + j] + b1[j];
            s_hl[tid] = v > 0.f ? v : 0.f;
        }
        __syncthreads();
        const int n4 = tid & 31, jg = tid >> 5;          // 32 float4-cols, 8 j-groups
        const float4* W24 = (const float4*)W2;           // row j = 128 float4
        float4 acc = make_float4(0.f, 0.f, 0.f, 0.f);
        #pragma unroll
        for (int i = 0; i < 4; ++i) {
            const int jloc = jg * 4 + i;
            const float hv = s_hl[jloc];
            const float4 w = W24[(jc * 32 + jloc) * 128 + nc * 32 + n4];
            acc.x += hv * w.x; acc.y += hv * w.y; acc.z += hv * w.z; acc.w += hv * w.w;
        }
        s_sm4[jg * 32 + n4] = acc;
        __syncthreads();
        if (tid < 32) {
            float4 r = make_float4(0.f, 0.f, 0.f, 0.f);
            #pragma unroll
            for (int g = 0; g < 8; ++g) {
                const float4 v = s_sm4[g * 32 + tid];
                r.x += v.x; r.y += v.y; r.z += v.z; r.w += v.w;
            }
            ((float4*)(ws + OFF_YPP))[jc * 128 + nc * 32 + tid] = r;
        }
        arrive_c(&cnt[3]);
    }

    // ---------------- P4.5: y combine + LN2 stats (blocks 0..3)
    if (bid < 4) {
        wait_c(&cnt[3], 256);
        const int nl = tid & 127, half = tid >> 7;
        float a = 0.f;
        #pragma unroll
        for (int j = 0; j < 32; ++j) {
            const int jc = half * 32 + j;
            a += ws[OFF_YPP + jc * 512 + bid * 128 + nl];
        }
        s_sm[tid] = a;
        __syncthreads();
        float y = 0.f;
        if (tid < 128) {
            y = s_sm[tid] + s_sm[128 + tid] + b2[bid * 128 + tid];
            ws[OFF_Y + bid * 128 + tid] = y;
        }
        const float su = block_reduce_256(tid < 128 ? y : 0.f, s_sred, tid);
        const float sq = block_reduce_256(tid < 128 ? y * y : 0.f, s_sred, tid);
        if (tid == 0) { ws[OFF_ST + bid] = su; ws[OFF_ST + 4 + bid] = sq; }
        arrive_c(&cnt[4]);
    }

    // ---------------- P5: LN2 apply + broadcast write (all 512 blocks)
    wait_c(&cnt[4], 4);
    const float mu = (ws[OFF_ST] + ws[OFF_ST + 1] + ws[OFF_ST + 2] + ws[OFF_ST + 3]) * (1.f / 512.f);
    const float ex2 = (ws[OFF_ST + 4] + ws[OFF_ST + 5] + ws[OFF_ST + 6] + ws[OFF_ST + 7]) * (1.f / 512.f);
    const float inv = rsqrtf(ex2 - mu * mu + LN_EPS);
    const float y0 = ws[OFF_Y + tid], y1 = ws[OFF_Y + 256 + tid];
    __syncthreads();  // all prior LDS uses done before overwrite
    s_big[tid]       = (y0 - mu) * inv * g2[tid] + be2[tid];
    s_big[tid + 256] = (y1 - mu) * inv * g2[tid + 256] + be2[tid + 256];
    __syncthreads();
    const float4* r4 = (const float4*)s_big;             // 128 float4
    float4* o4 = (float4*)out + bid * 1024;              // 8 rows per block
    #pragma unroll
    for (int i = 0; i < 4; ++i) {
        const int idx = i * 256 + tid;
        o4[idx] = r4[idx & 127];
    }
}

extern "C" void kernel_launch(void* const* d_in, const int* in_sizes, int n_in,
                              void* d_out, int out_size, void* d_ws, size_t ws_size,
                              hipStream_t stream) {
    const float* node = (const float*)d_in[0];
    // d_in[1] adjacency, d_in[2] Wks, d_in[3] Wqs — analytically unused
    const float* Wvs  = (const float*)d_in[4];
    const float* Wo   = (const float*)d_in[5];
    const float* W1   = (const float*)d_in[6];
    const float* b1   = (const float*)d_in[7];
    const float* W2   = (const float*)d_in[8];
    const float* b2   = (const float*)d_in[9];
    const float* g1   = (const float*)d_in[10];
    const float* be1  = (const float*)d_in[11];
    const float* g2   = (const float*)d_in[12];
    const float* be2  = (const float*)d_in[13];
    float* ws  = (float*)d_ws;
    int*   cnt = (int*)d_ws;
    float* out = (float*)d_out;

    hipMemsetAsync(d_ws, 0, 64, stream);  // zero the 8 phase counters
    fused_all<<<dim3(512), dim3(256), 0, stream>>>(node, Wvs, Wo, W1, b1, W2, b2,
                                                   g1, be1, g2, be2, ws, cnt, out);
}

// Round 5
// 166.471 us; speedup vs baseline: 1.6059x; 1.6059x over previous
//
#include <hip/hip_runtime.h>

#define LN_EPS 1e-5f

// d_ws layout: int counters at byte 0..31 (8 ints, memset to 0 per launch),
// float region offsets (in floats, all 16B-aligned):
#define OFF_NP   16      // 448   node partial sums (blocks 64..511)
#define OFF_CVP  464     // 64*64 cv partials [b=h*8+c][64]
#define OFF_S    4560    // 1 (pad 16)
#define OFF_TP   4576    // 4*512 t partials [rc][n]
#define OFF_HP   6624    // 4*2048 ffn1 partials [nq][j]
#define OFF_YPP  14816   // 64*512 ffn2 partials [jc][n]
#define OFF_Y    47584   // 512 y vector (pre-LN2)
#define OFF_ST   48096   // 8: sums[4], sumsqs[4]

__device__ inline float wave_reduce(float v) {
    #pragma unroll
    for (int o = 32; o > 0; o >>= 1) v += __shfl_xor(v, o);
    return v;
}

__device__ inline float block_reduce_256(float v, float* sred, int tid) {
    v = wave_reduce(v);
    if ((tid & 63) == 0) sred[tid >> 6] = v;
    __syncthreads();
    float r = sred[0] + sred[1] + sred[2] + sred[3];
    __syncthreads();
    return r;
}

__device__ inline void arrive_c(int* c) {
    __syncthreads();
    if (threadIdx.x == 0) {
        __threadfence();  // release: write back this CU's stores device-wide
        __hip_atomic_fetch_add(c, 1, __ATOMIC_RELEASE, __HIP_MEMORY_SCOPE_AGENT);
    }
}

// RELAXED poll (no per-iteration cache invalidate!) + sleep backoff;
// single acquire fence after the counter trips.
__device__ inline void wait_c(int* c, int target) {
    if (threadIdx.x == 0) {
        while (__hip_atomic_load(c, __ATOMIC_RELAXED, __HIP_MEMORY_SCOPE_AGENT) < target)
            __builtin_amdgcn_s_sleep(16);
    }
    __syncthreads();
    __threadfence();  // acquire: invalidate stale cached lines before data reads
}

__global__ __launch_bounds__(256, 2)
void fused_all(const float* __restrict__ node, const float* __restrict__ Wvs,
               const float* __restrict__ Wo, const float* __restrict__ W1,
               const float* __restrict__ b1, const float* __restrict__ W2,
               const float* __restrict__ b2, const float* __restrict__ g1,
               const float* __restrict__ be1, const float* __restrict__ g2,
               const float* __restrict__ be2, float* __restrict__ ws,
               int* __restrict__ cnt, float* __restrict__ out) {
    const int bid = blockIdx.x, tid = threadIdx.x;
    __shared__ float s_big[512];
    __shared__ float s_sm[256];
    __shared__ float4 s_sm4[256];
    __shared__ float s_sred[4];
    __shared__ float s_hl[32];

    // ---------------- P1: cv partials (blocks 0..63) / node partials (64..511)
    if (bid < 64) {
        const int h = bid >> 3, c = bid & 7;
        const int n = tid & 63, ks = tid >> 6;          // ks 0..3
        const float* w = Wvs + h * (512 * 64);
        float acc = 0.f;
        #pragma unroll
        for (int q = 0; q < 16; ++q) {
            const int k = c * 64 + ks + q * 4;
            acc += w[k * 64 + n];
        }
        s_sm[tid] = acc;
        __syncthreads();
        if (ks == 0)
            ws[OFF_CVP + bid * 64 + n] =
                s_sm[n] + s_sm[64 + n] + s_sm[128 + n] + s_sm[192 + n];
        arrive_c(&cnt[0]);          // cv producers: 64
    } else {
        const float4* n4 = (const float4*)node;          // 524288 float4
        const int base = (bid - 64) * 1171;
        float acc = 0.f;
        #pragma unroll
        for (int i = 0; i < 5; ++i) {
            const int off = i * 256 + tid;
            const int idx = base + off;
            if (off < 1171 && idx < 524288) {
                const float4 v = n4[idx];
                acc += (v.x + v.y) + (v.z + v.w);
            }
        }
        const float r = block_reduce_256(acc, s_sred, tid);
        if (tid == 0) ws[OFF_NP + (bid - 64)] = r;
        arrive_c(&cnt[1]);          // node producers: 448
    }

    // ---------------- P2: t partials (blocks 0..63) + S finalize (block 64)
    if (bid < 64) {
        wait_c(&cnt[0], 64);
        // build full cv[512] in LDS (r = h*64+m)
        #pragma unroll
        for (int half = 0; half < 2; ++half) {
            const int rr = tid + half * 256;
            const int hh = rr >> 6, mm = rr & 63;
            float a = 0.f;
            #pragma unroll
            for (int c = 0; c < 8; ++c) a += ws[OFF_CVP + (hh * 8 + c) * 64 + mm];
            s_big[rr] = a;
        }
        __syncthreads();
        const int rc = bid >> 4, nch = bid & 15;         // 4 r-chunks x 16 n-chunks
        const int nl = tid & 31, rg = tid >> 5;          // 32 n, 8 r-groups
        float acc = 0.f;
        #pragma unroll
        for (int i = 0; i < 16; ++i) {
            const int r = rc * 128 + rg * 16 + i;
            acc += s_big[r] * Wo[r * 512 + nch * 32 + nl];
        }
        s_sm[rg * 32 + nl] = acc;
        __syncthreads();
        if (tid < 32) {
            float s = 0.f;
            #pragma unroll
            for (int g = 0; g < 8; ++g) s += s_sm[g * 32 + tid];
            ws[OFF_TP + rc * 512 + nch * 32 + tid] = s;
        }
        arrive_c(&cnt[2]);          // t producers: 64
    } else if (bid == 64) {
        wait_c(&cnt[1], 448);
        float v = ws[OFF_NP + tid];
        if (tid < 192) v += ws[OFF_NP + 256 + tid];
        const float s = block_reduce_256(v, s_sred, tid);
        if (tid == 0) ws[OFF_S] = s;
        arrive_c(&cnt[2]);          // S producer: 1  (cnt[2] target = 65)
    }

    // ---------------- P3: LN1 (redundant) + FFN1 partial (blocks 0..255)
    if (bid < 256) {
        wait_c(&cnt[2], 65);
        const float S = ws[OFF_S];
        float x0, x1;
        {
            const int n = tid;
            x0 = S * (ws[OFF_TP + n] + ws[OFF_TP + 512 + n] +
                      ws[OFF_TP + 1024 + n] + ws[OFF_TP + 1536 + n]);
        }
        {
            const int n = tid + 256;
            x1 = S * (ws[OFF_TP + n] + ws[OFF_TP + 512 + n] +
                      ws[OFF_TP + 1024 + n] + ws[OFF_TP + 1536 + n]);
        }
        const float tot = block_reduce_256(x0 + x1, s_sred, tid);
        const float mu = tot * (1.f / 512.f);
        const float d0 = x0 - mu, d1 = x1 - mu;
        const float var = block_reduce_256(d0 * d0 + d1 * d1, s_sred, tid) * (1.f / 512.f);
        const float inv = rsqrtf(var + LN_EPS);
        s_big[tid]       = d0 * inv * g1[tid] + be1[tid];
        s_big[tid + 256] = d1 * inv * g1[tid + 256] + be1[tid + 256];
        __syncthreads();
        const int jc3 = bid >> 2, nq = bid & 3;          // 64 j-chunks x 4 n-quarters
        const int jl = tid & 31, ng = tid >> 5;          // 32 j, 8 n-groups
        float acc = 0.f;
        #pragma unroll
        for (int i = 0; i < 16; ++i) {
            const int n = nq * 128 + ng * 16 + i;
            acc += s_big[n] * W1[n * 2048 + jc3 * 32 + jl];
        }
        s_sm[ng * 32 + jl] = acc;
        __syncthreads();
        if (tid < 32) {
            float s = 0.f;
            #pragma unroll
            for (int g = 0; g < 8; ++g) s += s_sm[g * 32 + tid];
            ws[OFF_HP + nq * 2048 + jc3 * 32 + tid] = s;
        }
        arrive_c(&cnt[3]);          // FFN1 producers: 256
    }

    // ---------------- P4: h finalize + FFN2 partial (blocks 0..255)
    if (bid < 256) {
        wait_c(&cnt[3], 256);
        const int jc = bid >> 2, nc = bid & 3;           // 64 j-chunks x 4 n-chunks
        if (tid < 32) {
            const int j = jc * 32 + tid;
            const float v = ws[OFF_HP + j] + ws[OFF_HP + 2048 + j] +
                            ws[OFF_HP + 4096 + j] + ws[OFF_HP + 6144 + j] + b1[j];
            s_hl[tid] = v > 0.f ? v : 0.f;
        }
        __syncthreads();
        const int n4 = tid & 31, jg = tid >> 5;          // 32 float4-cols, 8 j-groups
        const float4* W24 = (const float4*)W2;           // row j = 128 float4
        float4 acc = make_float4(0.f, 0.f, 0.f, 0.f);
        #pragma unroll
        for (int i = 0; i < 4; ++i) {
            const int jloc = jg * 4 + i;
            const float hv = s_hl[jloc];
            const float4 w = W24[(jc * 32 + jloc) * 128 + nc * 32 + n4];
            acc.x += hv * w.x; acc.y += hv * w.y; acc.z += hv * w.z; acc.w += hv * w.w;
        }
        s_sm4[jg * 32 + n4] = acc;
        __syncthreads();
        if (tid < 32) {
            float4 r = make_float4(0.f, 0.f, 0.f, 0.f);
            #pragma unroll
            for (int g = 0; g < 8; ++g) {
                const float4 v = s_sm4[g * 32 + tid];
                r.x += v.x; r.y += v.y; r.z += v.z; r.w += v.w;
            }
            ((float4*)(ws + OFF_YPP))[jc * 128 + nc * 32 + tid] = r;
        }
        arrive_c(&cnt[4]);          // FFN2 producers: 256
    }

    // ---------------- P4.5: y combine + LN2 stats (blocks 0..3)
    if (bid < 4) {
        wait_c(&cnt[4], 256);
        const int nl = tid & 127, half = tid >> 7;
        float a = 0.f;
        #pragma unroll
        for (int j = 0; j < 32; ++j) {
            const int jc = half * 32 + j;
            a += ws[OFF_YPP + jc * 512 + bid * 128 + nl];
        }
        s_sm[tid] = a;
        __syncthreads();
        float y = 0.f;
        if (tid < 128) {
            y = s_sm[tid] + s_sm[128 + tid] + b2[bid * 128 + tid];
            ws[OFF_Y + bid * 128 + tid] = y;
        }
        const float su = block_reduce_256(tid < 128 ? y : 0.f, s_sred, tid);
        const float sq = block_reduce_256(tid < 128 ? y * y : 0.f, s_sred, tid);
        if (tid == 0) { ws[OFF_ST + bid] = su; ws[OFF_ST + 4 + bid] = sq; }
        arrive_c(&cnt[5]);          // stats producers: 4
    }

    // ---------------- P5: LN2 apply + broadcast write (all 512 blocks)
    wait_c(&cnt[5], 4);
    const float mu = (ws[OFF_ST] + ws[OFF_ST + 1] + ws[OFF_ST + 2] + ws[OFF_ST + 3]) * (1.f / 512.f);
    const float ex2 = (ws[OFF_ST + 4] + ws[OFF_ST + 5] + ws[OFF_ST + 6] + ws[OFF_ST + 7]) * (1.f / 512.f);
    const float inv = rsqrtf(ex2 - mu * mu + LN_EPS);
    const float y0 = ws[OFF_Y + tid], y1 = ws[OFF_Y + 256 + tid];
    __syncthreads();  // all prior LDS uses done before overwrite
    s_big[tid]       = (y0 - mu) * inv * g2[tid] + be2[tid];
    s_big[tid + 256] = (y1 - mu) * inv * g2[tid + 256] + be2[tid + 256];
    __syncthreads();
    const float4* r4 = (const float4*)s_big;             // 128 float4
    float4* o4 = (float4*)out + bid * 1024;              // 8 rows per block
    #pragma unroll
    for (int i = 0; i < 4; ++i) {
        const int idx = i * 256 + tid;
        o4[idx] = r4[idx & 127];
    }
}

extern "C" void kernel_launch(void* const* d_in, const int* in_sizes, int n_in,
                              void* d_out, int out_size, void* d_ws, size_t ws_size,
                              hipStream_t stream) {
    const float* node = (const float*)d_in[0];
    // d_in[1] adjacency, d_in[2] Wks, d_in[3] Wqs — analytically unused
    const float* Wvs  = (const float*)d_in[4];
    const float* Wo   = (const float*)d_in[5];
    const float* W1   = (const float*)d_in[6];
    const float* b1   = (const float*)d_in[7];
    const float* W2   = (const float*)d_in[8];
    const float* b2   = (const float*)d_in[9];
    const float* g1   = (const float*)d_in[10];
    const float* be1  = (const float*)d_in[11];
    const float* g2   = (const float*)d_in[12];
    const float* be2  = (const float*)d_in[13];
    float* ws  = (float*)d_ws;
    int*   cnt = (int*)d_ws;
    float* out = (float*)d_out;

    hipMemsetAsync(d_ws, 0, 64, stream);  // zero the phase counters
    fused_all<<<dim3(512), dim3(256), 0, stream>>>(node, Wvs, Wo, W1, b1, W2, b2,
                                                   g1, be1, g2, be2, ws, cnt, out);
}

// Round 6
// 23.077 us; speedup vs baseline: 11.5849x; 7.2138x over previous
//
#include <hip/hip_runtime.h>

#define LN_EPS 1e-5f

// ws float offsets
#define OFF_NP 0        // 448    node partial sums
#define OFF_TP 448      // 64*512 t partials [b = h*8+kc][n]
#define OFF_YP 33216    // 64*512 ffn2 partials [jc][n]
// end 65984 floats = 264 KB

__device__ inline float wave_reduce(float v) {
    #pragma unroll
    for (int o = 32; o > 0; o >>= 1) v += __shfl_xor(v, o);
    return v;
}

__device__ inline float block_reduce_256(float v, float* sred, int tid) {
    v = wave_reduce(v);
    if ((tid & 63) == 0) sred[tid >> 6] = v;
    __syncthreads();
    float r = sred[0] + sred[1] + sred[2] + sred[3];
    __syncthreads();
    return r;
}

__device__ inline float block_reduce_512(float v, float* sred, int tid) {
    v = wave_reduce(v);
    if ((tid & 63) == 0) sred[tid >> 6] = v;
    __syncthreads();
    float r = 0.f;
    #pragma unroll
    for (int i = 0; i < 8; ++i) r += sred[i];
    __syncthreads();
    return r;
}

// K1: blocks 0..63  -> direct t partials (cv-partial in LDS, then Wo GEMV)
//     blocks 64..511 -> node partial sums
__global__ void k1_tp_np(const float* __restrict__ node, const float* __restrict__ Wvs,
                         const float* __restrict__ Wo, float* __restrict__ ws) {
    const int bid = blockIdx.x, tid = threadIdx.x;  // 256 threads
    __shared__ float sm[256];
    __shared__ float cvp[64];
    __shared__ float sred[4];
    if (bid < 64) {
        const int h = bid >> 3, kc = bid & 7;
        // step 1: cv partial over this block's 64-k slice
        {
            const int m = tid & 63, ks = tid >> 6;   // ks 0..3
            const float* w = Wvs + h * (512 * 64);
            float acc = 0.f;
            #pragma unroll
            for (int q = 0; q < 16; ++q) {
                const int k = kc * 64 + ks + q * 4;
                acc += w[k * 64 + m];
            }
            sm[tid] = acc;
            __syncthreads();
            if (ks == 0) cvp[m] = sm[m] + sm[64 + m] + sm[128 + m] + sm[192 + m];
            __syncthreads();
        }
        // step 2: tp[n] = sum_m cvp[m] * Wo[h,m,n]; thread owns n=tid and tid+256
        const float* wo = Wo + h * (64 * 512);
        float a0 = 0.f, a1 = 0.f;
        #pragma unroll
        for (int m = 0; m < 64; ++m) {
            const float c = cvp[m];
            a0 += c * wo[m * 512 + tid];
            a1 += c * wo[m * 512 + tid + 256];
        }
        ws[OFF_TP + bid * 512 + tid]       = a0;
        ws[OFF_TP + bid * 512 + tid + 256] = a1;
    } else {
        const float4* n4 = (const float4*)node;      // 524288 float4
        const int base = (bid - 64) * 1171;
        float acc = 0.f;
        #pragma unroll
        for (int i = 0; i < 5; ++i) {
            const int off = i * 256 + tid;
            const int idx = base + off;
            if (off < 1171 && idx < 524288) {
                const float4 v = n4[idx];
                acc += (v.x + v.y) + (v.z + v.w);
            }
        }
        const float r = block_reduce_256(acc, sred, tid);
        if (tid == 0) ws[OFF_NP + (bid - 64)] = r;
    }
}

// K2: 64 blocks x 512 threads. Redundant {S, t, LN1}; final FFN1 for the block's
// 32-j chunk; FFN2 partial for that chunk.
__global__ void k2_ln1_ffn(const float* __restrict__ g1, const float* __restrict__ be1,
                           const float* __restrict__ W1, const float* __restrict__ b1,
                           const float* __restrict__ W2, float* __restrict__ ws) {
    const int jc = blockIdx.x, tid = threadIdx.x;
    __shared__ float xs[512];
    __shared__ float sm[512];
    __shared__ float sred[8];
    __shared__ float hl[32];
    // S (redundant per block)
    float v = (tid < 448) ? ws[OFF_NP + tid] : 0.f;
    const float S = block_reduce_512(v, sred, tid);
    // t[n] for n = tid
    float t = 0.f;
    #pragma unroll
    for (int b = 0; b < 64; ++b) t += ws[OFF_TP + b * 512 + tid];
    const float x = S * t;
    // LN1
    const float tot = block_reduce_512(x, sred, tid);
    const float mu = tot * (1.f / 512.f);
    const float d = x - mu;
    const float var = block_reduce_512(d * d, sred, tid) * (1.f / 512.f);
    const float inv = rsqrtf(var + LN_EPS);
    xs[tid] = d * inv * g1[tid] + be1[tid];
    __syncthreads();
    // FFN1: j = jc*32 + jl; 16 n-groups x 32 j-lanes
    {
        const int jl = tid & 31, ng = tid >> 5;
        float acc = 0.f;
        #pragma unroll
        for (int i = 0; i < 32; ++i) {
            const int n = ng + 16 * i;
            acc += xs[n] * W1[n * 2048 + jc * 32 + jl];
        }
        sm[ng * 32 + jl] = acc;
        __syncthreads();
        if (tid < 32) {
            float s = 0.f;
            #pragma unroll
            for (int g = 0; g < 16; ++g) s += sm[g * 32 + tid];
            const float hv = s + b1[jc * 32 + tid];
            hl[tid] = hv > 0.f ? hv : 0.f;
        }
        __syncthreads();
    }
    // FFN2 partial: thread owns n = tid; sum over this chunk's 32 j's
    float acc = 0.f;
    #pragma unroll
    for (int jl = 0; jl < 32; ++jl)
        acc += hl[jl] * W2[(jc * 32 + jl) * 512 + tid];
    ws[OFF_YP + jc * 512 + tid] = acc;
}

// K3: 128 blocks x 256 threads. Redundant {yp combine + b2 + LN2}; write 32 rows.
__global__ void k3_ln2_bcast(const float* __restrict__ b2, const float* __restrict__ g2,
                             const float* __restrict__ be2, const float* __restrict__ ws,
                             float* __restrict__ out) {
    const int bid = blockIdx.x, tid = threadIdx.x;
    __shared__ float row[512];
    __shared__ float sred[4];
    float y0 = b2[tid], y1 = b2[tid + 256];
    #pragma unroll
    for (int jc = 0; jc < 64; ++jc) {
        y0 += ws[OFF_YP + jc * 512 + tid];
        y1 += ws[OFF_YP + jc * 512 + tid + 256];
    }
    const float tot = block_reduce_256(y0 + y1, sred, tid);
    const float mu = tot * (1.f / 512.f);
    const float d0 = y0 - mu, d1 = y1 - mu;
    const float var = block_reduce_256(d0 * d0 + d1 * d1, sred, tid) * (1.f / 512.f);
    const float inv = rsqrtf(var + LN_EPS);
    row[tid]       = d0 * inv * g2[tid] + be2[tid];
    row[tid + 256] = d1 * inv * g2[tid + 256] + be2[tid + 256];
    __syncthreads();
    const float4* r4 = (const float4*)row;        // 128 float4
    float4* o4 = (float4*)out + bid * 4096;       // 32 rows per block
    #pragma unroll
    for (int i = 0; i < 16; ++i) {
        const int idx = i * 256 + tid;
        o4[idx] = r4[idx & 127];
    }
}

extern "C" void kernel_launch(void* const* d_in, const int* in_sizes, int n_in,
                              void* d_out, int out_size, void* d_ws, size_t ws_size,
                              hipStream_t stream) {
    const float* node = (const float*)d_in[0];
    // d_in[1] adjacency, d_in[2] Wks, d_in[3] Wqs — analytically unused
    const float* Wvs  = (const float*)d_in[4];
    const float* Wo   = (const float*)d_in[5];
    const float* W1   = (const float*)d_in[6];
    const float* b1   = (const float*)d_in[7];
    const float* W2   = (const float*)d_in[8];
    const float* b2   = (const float*)d_in[9];
    const float* g1   = (const float*)d_in[10];
    const float* be1  = (const float*)d_in[11];
    const float* g2   = (const float*)d_in[12];
    const float* be2  = (const float*)d_in[13];
    float* ws  = (float*)d_ws;
    float* out = (float*)d_out;

    k1_tp_np    <<<dim3(512), dim3(256), 0, stream>>>(node, Wvs, Wo, ws);
    k2_ln1_ffn  <<<dim3(64),  dim3(512), 0, stream>>>(g1, be1, W1, b1, W2, ws);
    k3_ln2_bcast<<<dim3(128), dim3(256), 0, stream>>>(b2, g2, be2, ws, out);
}

// Round 7
// 21.250 us; speedup vs baseline: 12.5807x; 1.0860x over previous
//
#include <hip/hip_runtime.h>

#define LN_EPS 1e-5f

// ws float offsets (16B-aligned)
#define OFF_NP 0        // 384          node partial sums
#define OFF_TP 384      // 32*512       t partials [p=h*4+kc][n]
#define OFF_HP 16768    // 4*2048       ffn1 partials [nq][j]
#define OFF_YP 24960    // 32*512       ffn2 partials [jc2][n]
// end 41344 floats = 165 KB

__device__ inline float wave_reduce(float v) {
    #pragma unroll
    for (int o = 32; o > 0; o >>= 1) v += __shfl_xor(v, o);
    return v;
}

__device__ inline float block_reduce_256(float v, float* sred, int tid) {
    v = wave_reduce(v);
    if ((tid & 63) == 0) sred[tid >> 6] = v;
    __syncthreads();
    float r = sred[0] + sred[1] + sred[2] + sred[3];
    __syncthreads();
    return r;
}

// K1: blocks 0..127  -> t partials, split (h, kc, nc): 8 heads x 4 k-chunks x 4 n-chunks
//     blocks 128..511 -> node partial sums (384 blocks)
__global__ void k1_tp_np(const float* __restrict__ node, const float* __restrict__ Wvs,
                         const float* __restrict__ Wo, float* __restrict__ ws) {
    const int bid = blockIdx.x, tid = threadIdx.x;  // 256 threads
    __shared__ float sm[256];
    __shared__ float cvp[64];
    __shared__ float sred[4];
    if (bid < 128) {
        const int h = bid >> 4, kc = (bid >> 2) & 3, nc = bid & 3;
        // step 1: cv partial over this block's 128-k slice (all 64 m)
        {
            const int m = tid & 63, ks = tid >> 6;       // ks 0..3
            const float* w = Wvs + h * (512 * 64);
            float acc = 0.f;
            #pragma unroll
            for (int q = 0; q < 32; ++q) {
                const int k = kc * 128 + q * 4 + ks;
                acc += w[k * 64 + m];
            }
            sm[tid] = acc;
            __syncthreads();
            if (ks == 0) cvp[m] = sm[m] + sm[64 + m] + sm[128 + m] + sm[192 + m];
            __syncthreads();
        }
        // step 2: tp[n] = sum_m cvp[m]*Wo[h,m,n] over the block's 128-n slice
        const int nl = tid & 127, half = tid >> 7;       // 2 m-halves
        const float* wo = Wo + h * (64 * 512);
        float acc = 0.f;
        #pragma unroll
        for (int i = 0; i < 32; ++i) {
            const int m = half * 32 + i;
            acc += cvp[m] * wo[m * 512 + nc * 128 + nl];  // 512B row slice
        }
        sm[half * 128 + nl] = acc;
        __syncthreads();
        if (tid < 128)
            ws[OFF_TP + (h * 4 + kc) * 512 + nc * 128 + tid] = sm[tid] + sm[128 + tid];
    } else {
        const float4* n4 = (const float4*)node;          // 524288 float4
        const int base = (bid - 128) * 1366;
        float acc = 0.f;
        #pragma unroll
        for (int i = 0; i < 6; ++i) {
            const int off = i * 256 + tid;
            const int idx = base + off;
            if (off < 1366 && idx < 524288) {
                const float4 v = n4[idx];
                acc += (v.x + v.y) + (v.z + v.w);
            }
        }
        const float r = block_reduce_256(acc, sred, tid);
        if (tid == 0) ws[OFF_NP + (bid - 128)] = r;
    }
}

// K2: 256 blocks x 256 threads. (jc = bid>>2: 64 j-chunks of 32; nq = bid&3: n-quarter).
// Redundant {S, t, LN1}; FFN1 partial over 128 n's for the 32-j chunk.
__global__ void k2_ln1_ffn1(const float* __restrict__ g1, const float* __restrict__ be1,
                            const float* __restrict__ W1, float* __restrict__ ws) {
    const int bid = blockIdx.x, tid = threadIdx.x;
    const int jc = bid >> 2, nq = bid & 3;
    __shared__ float xs[512];
    __shared__ float sm[256];
    __shared__ float sred[4];
    // S (redundant)
    float v = ws[OFF_NP + tid];
    if (tid < 128) v += ws[OFF_NP + 256 + tid];
    const float S = block_reduce_256(v, sred, tid);
    // t and LN1 (thread owns n = tid and tid+256)
    float t0 = 0.f, t1 = 0.f;
    #pragma unroll
    for (int p = 0; p < 32; ++p) {
        t0 += ws[OFF_TP + p * 512 + tid];
        t1 += ws[OFF_TP + p * 512 + tid + 256];
    }
    const float x0 = S * t0, x1 = S * t1;
    const float tot = block_reduce_256(x0 + x1, sred, tid);
    const float mu = tot * (1.f / 512.f);
    const float d0 = x0 - mu, d1 = x1 - mu;
    const float var = block_reduce_256(d0 * d0 + d1 * d1, sred, tid) * (1.f / 512.f);
    const float inv = rsqrtf(var + LN_EPS);
    xs[tid]       = d0 * inv * g1[tid] + be1[tid];
    xs[tid + 256] = d1 * inv * g1[tid + 256] + be1[tid + 256];
    __syncthreads();
    // FFN1 partial: j = jc*32 + jl; n in [nq*128, nq*128+128)
    const int jl = tid & 31, ng = tid >> 5;              // 8 n-groups
    float acc = 0.f;
    #pragma unroll
    for (int i = 0; i < 16; ++i) {
        const int n = nq * 128 + ng * 16 + i;
        acc += xs[n] * W1[n * 2048 + jc * 32 + jl];      // 128B row slice
    }
    sm[tid] = acc;
    __syncthreads();
    if (tid < 32) {
        float s = 0.f;
        #pragma unroll
        for (int g = 0; g < 8; ++g) s += sm[g * 32 + tid];
        ws[OFF_HP + nq * 2048 + jc * 32 + tid] = s;
    }
}

// K3: 256 blocks x 256 threads. (jc2 = bid>>3: 32 j-chunks of 64; nc = bid&7: 64-n slice).
// h finalize (+b1, ReLU) for the 64-j chunk; FFN2 partial for its 64-n slice.
__global__ void k3_ffn2(const float* __restrict__ b1, const float* __restrict__ W2,
                        float* __restrict__ ws) {
    const int bid = blockIdx.x, tid = threadIdx.x;
    const int jc2 = bid >> 3, nc = bid & 7;
    __shared__ float hl[64];
    __shared__ float sm[256];
    if (tid < 64) {
        const int j = jc2 * 64 + tid;
        const float v = ws[OFF_HP + j] + ws[OFF_HP + 2048 + j] +
                        ws[OFF_HP + 4096 + j] + ws[OFF_HP + 6144 + j] + b1[j];
        hl[tid] = v > 0.f ? v : 0.f;
    }
    __syncthreads();
    const int nl = tid & 63, q = tid >> 6;               // 4 j-quarters of 16
    float acc = 0.f;
    #pragma unroll
    for (int i = 0; i < 16; ++i) {
        const int jl = q * 16 + i;
        acc += hl[jl] * W2[(jc2 * 64 + jl) * 512 + nc * 64 + nl];  // 256B row slice
    }
    sm[tid] = acc;
    __syncthreads();
    if (tid < 64)
        ws[OFF_YP + jc2 * 512 + nc * 64 + tid] =
            sm[tid] + sm[64 + tid] + sm[128 + tid] + sm[192 + tid];
}

// K4: 256 blocks x 256 threads. Redundant {yp combine + b2 + LN2}; write 16 rows each.
__global__ void k4_ln2_bcast(const float* __restrict__ b2, const float* __restrict__ g2,
                             const float* __restrict__ be2, const float* __restrict__ ws,
                             float* __restrict__ out) {
    const int bid = blockIdx.x, tid = threadIdx.x;
    __shared__ float row[512];
    __shared__ float sred[4];
    float y0 = b2[tid], y1 = b2[tid + 256];
    #pragma unroll
    for (int p = 0; p < 32; ++p) {
        y0 += ws[OFF_YP + p * 512 + tid];
        y1 += ws[OFF_YP + p * 512 + tid + 256];
    }
    const float tot = block_reduce_256(y0 + y1, sred, tid);
    const float mu = tot * (1.f / 512.f);
    const float d0 = y0 - mu, d1 = y1 - mu;
    const float var = block_reduce_256(d0 * d0 + d1 * d1, sred, tid) * (1.f / 512.f);
    const float inv = rsqrtf(var + LN_EPS);
    row[tid]       = d0 * inv * g2[tid] + be2[tid];
    row[tid + 256] = d1 * inv * g2[tid + 256] + be2[tid + 256];
    __syncthreads();
    const float4* r4 = (const float4*)row;               // 128 float4
    float4* o4 = (float4*)out + bid * 2048;              // 16 rows per block
    #pragma unroll
    for (int i = 0; i < 8; ++i) {
        const int idx = i * 256 + tid;
        o4[idx] = r4[idx & 127];
    }
}

extern "C" void kernel_launch(void* const* d_in, const int* in_sizes, int n_in,
                              void* d_out, int out_size, void* d_ws, size_t ws_size,
                              hipStream_t stream) {
    const float* node = (const float*)d_in[0];
    // d_in[1] adjacency, d_in[2] Wks, d_in[3] Wqs — analytically unused
    const float* Wvs  = (const float*)d_in[4];
    const float* Wo   = (const float*)d_in[5];
    const float* W1   = (const float*)d_in[6];
    const float* b1   = (const float*)d_in[7];
    const float* W2   = (const float*)d_in[8];
    const float* b2   = (const float*)d_in[9];
    const float* g1   = (const float*)d_in[10];
    const float* be1  = (const float*)d_in[11];
    const float* g2   = (const float*)d_in[12];
    const float* be2  = (const float*)d_in[13];
    float* ws  = (float*)d_ws;
    float* out = (float*)d_out;

    k1_tp_np    <<<dim3(512), dim3(256), 0, stream>>>(node, Wvs, Wo, ws);
    k2_ln1_ffn1 <<<dim3(256), dim3(256), 0, stream>>>(g1, be1, W1, ws);
    k3_ffn2     <<<dim3(256), dim3(256), 0, stream>>>(b1, W2, ws);
    k4_ln2_bcast<<<dim3(256), dim3(256), 0, stream>>>(b2, g2, be2, ws, out);
}

// Round 8
// 21.050 us; speedup vs baseline: 12.7005x; 1.0095x over previous
//
#include <hip/hip_runtime.h>

#define LN_EPS 1e-5f

// ws float offsets (16B-aligned)
#define OFF_NP 0        // 384            node partial sums
#define OFF_TP 384      // 64*512=32768   t partials [p=(h*4+kc)*2+mc][n]
#define OFF_HP 33152    // 8*2048=16384   ffn1 partials [nq][j]
#define OFF_YP 49536    // 32*512=16384   ffn2 partials [jc2][n]
// end 65920 floats = 264 KB

__device__ inline float wave_reduce(float v) {
    #pragma unroll
    for (int o = 32; o > 0; o >>= 1) v += __shfl_xor(v, o);
    return v;
}

__device__ inline float block_reduce_256(float v, float* sred, int tid) {
    v = wave_reduce(v);
    if ((tid & 63) == 0) sred[tid >> 6] = v;
    __syncthreads();
    float r = sred[0] + sred[1] + sred[2] + sred[3];
    __syncthreads();
    return r;
}

// K1: blocks 0..255  -> t partials (h x kc(4 k-chunks) x mc(2 m-halves) x nc(4 n-chunks))
//     blocks 256..639 -> node partial sums (384 blocks)
__global__ void k1_tp_np(const float* __restrict__ node, const float* __restrict__ Wvs,
                         const float* __restrict__ Wo, float* __restrict__ ws) {
    const int bid = blockIdx.x, tid = threadIdx.x;  // 256 threads
    __shared__ float4 s_sm4[256];
    __shared__ float s_cvp[32];
    __shared__ float s_sm[256];
    __shared__ float s_sred[4];
    if (bid < 256) {
        const int h = bid >> 5, kc = (bid >> 3) & 3, mc = (bid >> 2) & 1, nc = bid & 3;
        // step 1: cv partial over 128 k's, 32 m's (float4 across m)
        const float4* Wvs4 = (const float4*)(Wvs + h * (512 * 64));  // [512][16]
        const int m4 = tid & 7, kg = tid >> 3;        // 8 float4 m-cols, 32 k-groups
        float4 a = make_float4(0.f, 0.f, 0.f, 0.f);
        #pragma unroll
        for (int i = 0; i < 4; ++i) {
            const int k = kc * 128 + kg * 4 + i;
            const float4 v = Wvs4[k * 16 + mc * 8 + m4];
            a.x += v.x; a.y += v.y; a.z += v.z; a.w += v.w;
        }
        s_sm4[tid] = a;
        __syncthreads();
        if (tid < 8) {
            float4 cs = make_float4(0.f, 0.f, 0.f, 0.f);
            for (int g = 0; g < 32; ++g) {
                const float4 v = s_sm4[g * 8 + tid];
                cs.x += v.x; cs.y += v.y; cs.z += v.z; cs.w += v.w;
            }
            s_cvp[tid * 4 + 0] = cs.x; s_cvp[tid * 4 + 1] = cs.y;
            s_cvp[tid * 4 + 2] = cs.z; s_cvp[tid * 4 + 3] = cs.w;
        }
        __syncthreads();
        // step 2: tp[n] = sum over 32 m of cvp[m]*Wo[h][mc*32+m][nc*128+nl]
        const int nl = tid & 127, mg = tid >> 7;      // 128 n, 2 m-groups of 16
        const float* wo = Wo + h * (64 * 512) + (mc * 32 + mg * 16) * 512 + nc * 128 + nl;
        float acc = 0.f;
        #pragma unroll
        for (int i = 0; i < 16; ++i)
            acc += s_cvp[mg * 16 + i] * wo[i * 512];
        s_sm[tid] = acc;
        __syncthreads();
        if (tid < 128)
            ws[OFF_TP + (bid >> 2) * 512 + nc * 128 + tid] = s_sm[tid] + s_sm[128 + tid];
    } else {
        const float4* n4 = (const float4*)node;       // 524288 float4
        const int base = (bid - 256) * 1366;
        float acc = 0.f;
        #pragma unroll
        for (int i = 0; i < 6; ++i) {
            const int off = i * 256 + tid;
            const int idx = base + off;
            if (off < 1366 && idx < 524288) {
                const float4 v = n4[idx];
                acc += (v.x + v.y) + (v.z + v.w);
            }
        }
        const float r = block_reduce_256(acc, s_sred, tid);
        if (tid == 0) ws[OFF_NP + (bid - 256)] = r;
    }
}

// K2: 128 blocks x 256 threads (jc = 16 chunks of 128 j = 32 float4; nq = 8 chunks of 64 n).
// W1 float4 loads issued FIRST; redundant {S, t, LN1} prefix runs under their latency.
__global__ void k2_ln1_ffn1(const float* __restrict__ g1, const float* __restrict__ be1,
                            const float* __restrict__ W1, float* __restrict__ ws) {
    const int bid = blockIdx.x, tid = threadIdx.x;
    const int jc = bid >> 3, nq = bid & 7;
    __shared__ float4 s_sm4[256];
    __shared__ float s_xs[512];
    __shared__ float s_sred[4];
    // --- issue weight loads first (independent of prefix) ---
    const float4* W14 = (const float4*)W1;            // row n = 512 float4
    const int jl4 = tid & 31, ng = tid >> 5;          // 32 j-float4, 8 n-groups
    float4 w[8];
    #pragma unroll
    for (int i = 0; i < 8; ++i) {
        const int n = nq * 64 + ng * 8 + i;
        w[i] = W14[n * 512 + jc * 32 + jl4];
    }
    // --- S (redundant) ---
    float v = ws[OFF_NP + tid];
    if (tid < 128) v += ws[OFF_NP + 256 + tid];
    const float S = block_reduce_256(v, s_sred, tid);
    // --- t combine (float4 over n) ---
    const float4* TP4 = (const float4*)(ws + OFF_TP); // [64][128]
    const int c = tid & 127, ph = tid >> 7;
    float4 ts = make_float4(0.f, 0.f, 0.f, 0.f);
    #pragma unroll
    for (int p = 0; p < 32; ++p) {
        const float4 u = TP4[(ph * 32 + p) * 128 + c];
        ts.x += u.x; ts.y += u.y; ts.z += u.z; ts.w += u.w;
    }
    s_sm4[tid] = ts;
    __syncthreads();
    float4 x4 = make_float4(0.f, 0.f, 0.f, 0.f);
    float su = 0.f, sq = 0.f;
    if (tid < 128) {
        const float4 ua = s_sm4[tid], ub = s_sm4[128 + tid];
        x4.x = S * (ua.x + ub.x); x4.y = S * (ua.y + ub.y);
        x4.z = S * (ua.z + ub.z); x4.w = S * (ua.w + ub.w);
        su = (x4.x + x4.y) + (x4.z + x4.w);
        sq = x4.x * x4.x + x4.y * x4.y + x4.z * x4.z + x4.w * x4.w;
    }
    const float tot = block_reduce_256(su, s_sred, tid);
    const float mu = tot * (1.f / 512.f);
    const float sqt = block_reduce_256(sq, s_sred, tid);
    const float inv = rsqrtf(sqt * (1.f / 512.f) - mu * mu + LN_EPS);
    if (tid < 128) {
        const float4 gg = ((const float4*)g1)[tid];
        const float4 bb = ((const float4*)be1)[tid];
        float4 xh;
        xh.x = (x4.x - mu) * inv * gg.x + bb.x;
        xh.y = (x4.y - mu) * inv * gg.y + bb.y;
        xh.z = (x4.z - mu) * inv * gg.z + bb.z;
        xh.w = (x4.w - mu) * inv * gg.w + bb.w;
        ((float4*)s_xs)[tid] = xh;
    }
    __syncthreads();
    // --- FFN1 partial ---
    float4 acc = make_float4(0.f, 0.f, 0.f, 0.f);
    #pragma unroll
    for (int i = 0; i < 8; ++i) {
        const float xv = s_xs[nq * 64 + ng * 8 + i];
        acc.x += xv * w[i].x; acc.y += xv * w[i].y;
        acc.z += xv * w[i].z; acc.w += xv * w[i].w;
    }
    s_sm4[tid] = acc;
    __syncthreads();
    if (tid < 32) {
        float4 r = make_float4(0.f, 0.f, 0.f, 0.f);
        #pragma unroll
        for (int g = 0; g < 8; ++g) {
            const float4 u = s_sm4[g * 32 + tid];
            r.x += u.x; r.y += u.y; r.z += u.z; r.w += u.w;
        }
        ((float4*)(ws + OFF_HP))[nq * 512 + jc * 32 + tid] = r;
    }
}

// K3: 128 blocks x 256 threads (jc2 = 32 chunks of 64 j; nc4 = 4 chunks of 32 float4-n).
// W2 float4 loads first; h finalize (+b1, ReLU) under their latency.
__global__ void k3_ffn2(const float* __restrict__ b1, const float* __restrict__ W2,
                        float* __restrict__ ws) {
    const int bid = blockIdx.x, tid = threadIdx.x;
    const int jc2 = bid >> 2, nc4 = bid & 3;
    __shared__ float s_hl[64];
    __shared__ float4 s_sm4[256];
    const float4* W24 = (const float4*)W2;            // row j = 128 float4
    const int nl4 = tid & 31, q = tid >> 5;           // 32 n-float4, 8 j-groups
    float4 w[8];
    #pragma unroll
    for (int i = 0; i < 8; ++i) {
        const int j = jc2 * 64 + q * 8 + i;
        w[i] = W24[j * 128 + nc4 * 32 + nl4];
    }
    if (tid < 64) {
        const int j = jc2 * 64 + tid;
        float hv = b1[j];
        #pragma unroll
        for (int p = 0; p < 8; ++p) hv += ws[OFF_HP + p * 2048 + j];
        s_hl[tid] = hv > 0.f ? hv : 0.f;
    }
    __syncthreads();
    float4 acc = make_float4(0.f, 0.f, 0.f, 0.f);
    #pragma unroll
    for (int i = 0; i < 8; ++i) {
        const float hv = s_hl[q * 8 + i];
        acc.x += hv * w[i].x; acc.y += hv * w[i].y;
        acc.z += hv * w[i].z; acc.w += hv * w[i].w;
    }
    s_sm4[tid] = acc;
    __syncthreads();
    if (tid < 32) {
        float4 r = make_float4(0.f, 0.f, 0.f, 0.f);
        #pragma unroll
        for (int g = 0; g < 8; ++g) {
            const float4 u = s_sm4[g * 32 + tid];
            r.x += u.x; r.y += u.y; r.z += u.z; r.w += u.w;
        }
        ((float4*)(ws + OFF_YP))[jc2 * 128 + nc4 * 32 + tid] = r;
    }
}

// K4: 256 blocks x 256 threads. Redundant {yp float4 combine + b2 + LN2}; 16 rows each.
__global__ void k4_ln2_bcast(const float* __restrict__ b2, const float* __restrict__ g2,
                             const float* __restrict__ be2, const float* __restrict__ ws,
                             float* __restrict__ out) {
    const int bid = blockIdx.x, tid = threadIdx.x;
    __shared__ float4 s_sm4[256];
    __shared__ float4 s_row4[128];
    __shared__ float s_sred[4];
    const float4* YP4 = (const float4*)(ws + OFF_YP); // [32][128]
    const int c = tid & 127, ph = tid >> 7;
    float4 a = make_float4(0.f, 0.f, 0.f, 0.f);
    #pragma unroll
    for (int p = 0; p < 16; ++p) {
        const float4 u = YP4[(ph * 16 + p) * 128 + c];
        a.x += u.x; a.y += u.y; a.z += u.z; a.w += u.w;
    }
    s_sm4[tid] = a;
    __syncthreads();
    float4 y4 = make_float4(0.f, 0.f, 0.f, 0.f);
    float su = 0.f, sq = 0.f;
    if (tid < 128) {
        const float4 ua = s_sm4[tid], ub = s_sm4[128 + tid];
        const float4 bb = ((const float4*)b2)[tid];
        y4.x = ua.x + ub.x + bb.x; y4.y = ua.y + ub.y + bb.y;
        y4.z = ua.z + ub.z + bb.z; y4.w = ua.w + ub.w + bb.w;
        su = (y4.x + y4.y) + (y4.z + y4.w);
        sq = y4.x * y4.x + y4.y * y4.y + y4.z * y4.z + y4.w * y4.w;
    }
    const float tot = block_reduce_256(su, s_sred, tid);
    const float mu = tot * (1.f / 512.f);
    const float sqt = block_reduce_256(sq, s_sred, tid);
    const float inv = rsqrtf(sqt * (1.f / 512.f) - mu * mu + LN_EPS);
    if (tid < 128) {
        const float4 gg = ((const float4*)g2)[tid];
        const float4 bb = ((const float4*)be2)[tid];
        float4 r;
        r.x = (y4.x - mu) * inv * gg.x + bb.x;
        r.y = (y4.y - mu) * inv * gg.y + bb.y;
        r.z = (y4.z - mu) * inv * gg.z + bb.z;
        r.w = (y4.w - mu) * inv * gg.w + bb.w;
        s_row4[tid] = r;
    }
    __syncthreads();
    float4* o4 = (float4*)out + bid * 2048;           // 16 rows per block
    #pragma unroll
    for (int i = 0; i < 8; ++i) {
        const int idx = i * 256 + tid;
        o4[idx] = s_row4[idx & 127];
    }
}

extern "C" void kernel_launch(void* const* d_in, const int* in_sizes, int n_in,
                              void* d_out, int out_size, void* d_ws, size_t ws_size,
                              hipStream_t stream) {
    const float* node = (const float*)d_in[0];
    // d_in[1] adjacency, d_in[2] Wks, d_in[3] Wqs — analytically unused
    const float* Wvs  = (const float*)d_in[4];
    const float* Wo   = (const float*)d_in[5];
    const float* W1   = (const float*)d_in[6];
    const float* b1   = (const float*)d_in[7];
    const float* W2   = (const float*)d_in[8];
    const float* b2   = (const float*)d_in[9];
    const float* g1   = (const float*)d_in[10];
    const float* be1  = (const float*)d_in[11];
    const float* g2   = (const float*)d_in[12];
    const float* be2  = (const float*)d_in[13];
    float* ws  = (float*)d_ws;
    float* out = (float*)d_out;

    k1_tp_np    <<<dim3(640), dim3(256), 0, stream>>>(node, Wvs, Wo, ws);
    k2_ln1_ffn1 <<<dim3(128), dim3(256), 0, stream>>>(g1, be1, W1, ws);
    k3_ffn2     <<<dim3(128), dim3(256), 0, stream>>>(b1, W2, ws);
    k4_ln2_bcast<<<dim3(256), dim3(256), 0, stream>>>(b2, g2, be2, ws, out);
}